// Round 12
// baseline (3624.578 us; speedup 1.0000x reference)
//
#include <hip/hip_runtime.h>

typedef _Float16 f16x8 __attribute__((ext_vector_type(8)));
typedef float    f32x4 __attribute__((ext_vector_type(4)));
typedef unsigned long long u64;
typedef u64 u64x2 __attribute__((ext_vector_type(2)));

constexpr int BATCH = 1024;
constexpr int HDIM  = 512;
constexpr int TENC  = 512;
constexpr int PRED  = 48;
constexpr int STEPS = TENC + PRED - 1;   // 559 cell steps; loop runs 560 (last = fc only)
constexpr int NG    = 64;                // groups (16 batches each)
constexpr int GB    = 16;                // batches per group = one MFMA m-tile
constexpr int UBU   = 64;                // units per block (4 waves x 16)
constexpr int HB_OFF = 32768;
constexpr int NWORK = 256;               // worker blocks; blocks >= NWORK are burners

// In-band tag (R7/R8-proven): each 4B dword of stored h carries step tag at
// bit0/bit16. h_t in buffer t&1, tag t&3; skew <= 1 step => ABA-safe.
// LLC scope only (R10: per-XCD L2 is NOT a usable exchange medium).
constexpr u64 TAG_MASK = 0x0001000100010001ull;
__device__ __forceinline__ u64 tag_of(int t) {
  return ((u64)(t & 1) | ((u64)((t >> 1) & 1) << 16)) * 0x0000000100000001ull;
}

__global__ void init_kernel(int* wsi) {
  int idx = blockIdx.x * blockDim.x + threadIdx.x;
  int stride = gridDim.x * blockDim.x;
  const int nws = (HB_OFF + BATCH * HDIM * 2) / 4;  // done ctr + hbuf[0]=h_0=0
  for (int i = idx; i < nws; i += stride) wsi[i] = 0;
  // hbuf[1] stays 0xAA poison -> tag-invalid until written
}

static __device__ __forceinline__ f16x8 load16_llc(const _Float16* p) {
  f16x8 v;
  asm volatile("global_load_dwordx4 %0, %1, off sc0 sc1"
               : "=v"(v) : "v"((u64)p) : "memory");
  return v;
}
static __device__ __forceinline__ float loadx(const float* p) {
  float v;   // plain cached load via asm so compiler never vmcnt(0)-drains our prefetch
  asm volatile("global_load_dword %0, %1, off"
               : "=v"(v) : "v"((u64)p) : "memory");
  return v;
}

// R11 worker (passed, 3497us) + burner blocks. Workers are latency-bound and
// idle ~60% -> DPM holds core clock at ~920 MHz (measured via MFMA-busy vs
// counted MFMA cycles). Burner blocks (bid>=256) run full-rate v_fmac_f32
// with zero memory traffic to keep the CUs hot and the clock up; they exit
// when the done-counter hits NWORK. 2 blocks/CU fit (VGPR/LDS checked).
__global__ __launch_bounds__(256, 1) void lstm_persist(
    const float* __restrict__ x,
    const float* __restrict__ w_ih,
    const float* __restrict__ w_hh,
    const float* __restrict__ b_ih,
    const float* __restrict__ b_hh,
    const float* __restrict__ w_fc,
    const float* __restrict__ b_fc,
    float* __restrict__ out,          // [1024][48] fp32, plain stores
    _Float16* __restrict__ hbuf,      // [2][1024][512] fp16 ping-pong, tagged
    int* __restrict__ wsi)            // wsi[0] = worker done counter
{
  const int bid  = blockIdx.x;
  const int tid  = threadIdx.x;

  if (bid >= NWORK) {                 // ---- burner: pure VALU heat ----
    float a = (float)tid, b = 1.0000001f, c = 1e-9f;
    for (;;) {
      for (int i = 0; i < 4096; ++i)
        asm volatile("v_fmac_f32 %0, %1, %2" : "+v"(a) : "v"(b), "v"(c));
      if (__hip_atomic_load(&wsi[0], __ATOMIC_RELAXED,
                            __HIP_MEMORY_SCOPE_AGENT) >= NWORK) break;
    }
    if (a == 12345.678f) out[0] = a;  // defeat DCE (never true)
    return;
  }

  const int gA   = bid >> 3;          // group A (0..31); B = gA+32
  const int ub   = bid & 7;
  const int wid  = tid >> 6;
  const int lane = tid & 63;
  const int quad = lane >> 4;
  const int lcol = lane & 15;
  const int bA0  = gA * GB;
  const int bB0  = bA0 + NG / 2 * GB; // = bA0 + 512
  const int myu  = ub * UBU + wid * 16 + lcol;
  const int uoff = ub * UBU + wid * 16 + (lcol & ~3);

  __shared__ __align__(16) _Float16 hsA[GB][520];    // 16.6 KB
  __shared__ __align__(16) _Float16 hsB[GB][520];    // 16.6 KB
  __shared__ __align__(16) _Float16 wz[520];         // fp16 w_fc + zero pad

  for (int k = tid; k < 512; k += 256) wz[k] = (_Float16)w_fc[k];
  if (tid < 8) wz[512 + tid] = (_Float16)0.f;

  // ---- full-K weight B-frags (n=lcol, k=kc*32+quad*8+j) ----
  f16x8 wf[4][16];
  float wih[4], bias[4];
#pragma unroll
  for (int nt = 0; nt < 4; ++nt) {
    const int j = nt * HDIM + myu;
    wih[nt]  = w_ih[j];
    bias[nt] = b_ih[j] + b_hh[j];
#pragma unroll
    for (int kc = 0; kc < 16; ++kc) {
      const float* s = w_hh + (size_t)j * HDIM + kc * 32 + quad * 8;
      f16x8 v;
#pragma unroll
      for (int i = 0; i < 8; ++i) v[i] = (_Float16)s[i];
      wf[nt][kc] = v;
    }
  }
  const float bfc = b_fc[0];

  float cstA[4], cstB[4];
#pragma unroll
  for (int r = 0; r < 4; ++r) { cstA[r] = 0.f; cstB[r] = 0.f; }

  // staging: 16 rows x 512 units = 1024 16B-chunks; thread covers 4
  // (c = i*256+tid: row=c>>6, col16=c&63). Own slice included (own
  // store->load via LLC is same-thread ordered; R7-verified).
  f16x8 tA[4], tB[4];

  auto issue4 = [&](f16x8* tr, const _Float16* base) {
#pragma unroll
    for (int i = 0; i < 4; ++i) {
      const int c = i * 256 + tid;
      tr[i] = load16_llc(base + (size_t)(c >> 6) * HDIM + (c & 63) * 8);
    }
  };
  auto validate4 = [&](f16x8* tr, const _Float16* base, u64 expect) {
    unsigned stale = 0xf;
    for (;;) {
      unsigned ns = 0;
#pragma unroll
      for (int i = 0; i < 4; ++i)
        if (stale & (1u << i)) {
          u64x2 w2 = __builtin_bit_cast(u64x2, tr[i]);
          if (((w2[0] & TAG_MASK) != expect) || ((w2[1] & TAG_MASK) != expect))
            ns |= 1u << i;
        }
      if (ns == 0) break;
      __builtin_amdgcn_s_sleep(1);
#pragma unroll
      for (int i = 0; i < 4; ++i)
        if (ns & (1u << i)) {
          const int c = i * 256 + tid;
          tr[i] = load16_llc(base + (size_t)(c >> 6) * HDIM + (c & 63) * 8);
        }
      asm volatile("s_waitcnt vmcnt(0)" ::: "memory");
      stale = ns;
    }
  };
  auto stage4 = [&](f16x8* tr, _Float16 (*hsp)[520]) {
#pragma unroll
    for (int i = 0; i < 4; ++i) {
      const int c = i * 256 + tid;
      *reinterpret_cast<f16x8*>(&hsp[c >> 6][(c & 63) * 8]) = tr[i];
    }
  };
  auto gemm = [&](const _Float16 (*hsp)[520], f32x4* acc, f32x4& accF, bool dec) {
#pragma unroll
    for (int kc = 0; kc < 16; ++kc) {
      const f16x8 a = *reinterpret_cast<const f16x8*>(&hsp[lcol][kc * 32 + quad * 8]);
#pragma unroll
      for (int nt = 0; nt < 4; ++nt)
        acc[nt] = __builtin_amdgcn_mfma_f32_16x16x32_f16(a, wf[nt][kc], acc[nt], 0, 0, 0);
      if (dec) {   // fc: B row 0 = w_fc, rows 1..15 = 0 (zero-pad broadcast)
        const f16x8 wv = *reinterpret_cast<const f16x8*>(
            &wz[(lcol == 0) ? (kc * 32 + quad * 8) : 512]);
        accF = __builtin_amdgcn_mfma_f32_16x16x32_f16(a, wv, accF, 0, 0, 0);
      }
    }
  };
  auto tail = [&](f32x4* acc, f32x4& accF, float* xv, float* cstv,
                  int bX0, int t, _Float16* hnxt, bool dec) {
    if (dec) {   // xt = fc(h_t), redundant per block; preds stored by ub0/w0
#pragma unroll
      for (int r = 0; r < 4; ++r) xv[r] = __shfl(accF[r], quad * 16) + bfc;
      if (ub == 0 && wid == 0 && lcol == 0) {
        const int p = t - TENC;
#pragma unroll
        for (int r = 0; r < 4; ++r)
          out[(size_t)(bX0 + quad * 4 + r) * PRED + p] = accF[r] + bfc;
      }
    }
    if (t < STEPS) {
      const u64 tagnew = tag_of(t + 1);
#pragma unroll
      for (int r = 0; r < 4; ++r) {
        const float xt = xv[r];
        const float gi = acc[0][r] + xt * wih[0] + bias[0];
        const float gf = acc[1][r] + xt * wih[1] + bias[1];
        const float gg = acc[2][r] + xt * wih[2] + bias[2];
        const float go = acc[3][r] + xt * wih[3] + bias[3];
        const float si = 1.f / (1.f + __expf(-gi));
        const float sf = 1.f / (1.f + __expf(-gf));
        const float so = 1.f / (1.f + __expf(-go));
        const float tg = 1.f - 2.f / (1.f + __expf(2.f * gg));
        const float cn = sf * cstv[r] + si * tg;
        cstv[r] = cn;
        const float tc = 1.f - 2.f / (1.f + __expf(2.f * cn));
        const float hn = so * tc;

        const unsigned short hb = __builtin_bit_cast(unsigned short, (_Float16)hn);
        const unsigned v0  = hb;
        const unsigned o0  = (unsigned)__shfl_xor((int)v0, 1);
        const unsigned p01 = (lcol & 1) ? ((v0 << 16) | o0) : ((o0 << 16) | v0);
        const unsigned q   = (unsigned)__shfl_xor((int)p01, 2);
        u64 p4 = (lcol & 2) ? (((u64)p01 << 32) | (u64)q)
                            : (((u64)q << 32) | (u64)p01);
        p4 = (p4 & ~TAG_MASK) | tagnew;
        if ((lcol & 3) == r) {
          _Float16* dst = hnxt + (size_t)(bX0 + quad * 4 + r) * HDIM + uoff;
          __hip_atomic_store((u64*)dst, p4, __ATOMIC_RELAXED,
                             __HIP_MEMORY_SCOPE_AGENT);
        }
      }
    }
  };

  issue4(tA, hbuf + (size_t)bA0 * HDIM);   // prologue: A(0) in flight

  for (int t = 0; t <= STEPS; ++t) {
    const _Float16* hcur = hbuf + (size_t)(t & 1) * BATCH * HDIM;
    _Float16*       hnxt = hbuf + (size_t)((t + 1) & 1) * BATCH * HDIM;
    const u64 expect = tag_of(t);
    const bool dec = (t >= TENC);

    // ================= phase A =================
    float xA[4];
    if (!dec) {
#pragma unroll
      for (int r = 0; r < 4; ++r)
        xA[r] = loadx(x + (size_t)(bA0 + quad * 4 + r) * TENC + t);
    }
    asm volatile("s_waitcnt vmcnt(0)" ::: "memory");   // tA (+xA) landed
    validate4(tA, hcur + (size_t)bA0 * HDIM, expect);
    stage4(tA, hsA);
    __syncthreads();
    issue4(tB, hcur + (size_t)bB0 * HDIM);             // B(t) flies during A compute

    f32x4 accA[4], accFA;
#pragma unroll
    for (int nt = 0; nt < 4; ++nt) accA[nt] = (f32x4){0.f, 0.f, 0.f, 0.f};
    accFA = (f32x4){0.f, 0.f, 0.f, 0.f};
    gemm(hsA, accA, accFA, dec);
    tail(accA, accFA, xA, cstA, bA0, t, hnxt, dec);

    // ================= phase B =================
    float xB[4];
    if (!dec) {
#pragma unroll
      for (int r = 0; r < 4; ++r)
        xB[r] = loadx(x + (size_t)(bB0 + quad * 4 + r) * TENC + t);
    }
    asm volatile("s_waitcnt vmcnt(0)" ::: "memory");   // tB (+xB, A-publish) landed
    validate4(tB, hcur + (size_t)bB0 * HDIM, expect);
    stage4(tB, hsB);
    __syncthreads();
    if (t < STEPS)
      issue4(tA, hnxt + (size_t)bA0 * HDIM);           // A(t+1) flies during B compute

    f32x4 accB[4], accFB;
#pragma unroll
    for (int nt = 0; nt < 4; ++nt) accB[nt] = (f32x4){0.f, 0.f, 0.f, 0.f};
    accFB = (f32x4){0.f, 0.f, 0.f, 0.f};
    gemm(hsB, accB, accFB, dec);
    tail(accB, accFB, xB, cstB, bB0, t, hnxt, dec);
  }

  // ---- signal burners ----
  if (tid == 0)
    __hip_atomic_fetch_add(&wsi[0], 1, __ATOMIC_RELAXED,
                           __HIP_MEMORY_SCOPE_AGENT);
}

extern "C" void kernel_launch(void* const* d_in, const int* in_sizes, int n_in,
                              void* d_out, int out_size, void* d_ws, size_t ws_size,
                              hipStream_t stream) {
  const float* x    = (const float*)d_in[0];
  const float* w_ih = (const float*)d_in[1];
  const float* w_hh = (const float*)d_in[2];
  const float* b_ih = (const float*)d_in[3];
  const float* b_hh = (const float*)d_in[4];
  const float* w_fc = (const float*)d_in[5];
  const float* b_fc = (const float*)d_in[6];
  float* out = (float*)d_out;
  _Float16* hbuf = (_Float16*)((char*)d_ws + HB_OFF);

  hipLaunchKernelGGL(init_kernel, dim3(256), dim3(256), 0, stream, (int*)d_ws);
  hipLaunchKernelGGL(lstm_persist, dim3(2 * NWORK), dim3(256), 0, stream,
                     x, w_ih, w_hh, b_ih, b_hh, w_fc, b_fc, out, hbuf, (int*)d_ws);
}

// Round 13
// 3558.538 us; speedup vs baseline: 1.0186x; 1.0186x over previous
//
#include <hip/hip_runtime.h>

typedef _Float16 f16x8 __attribute__((ext_vector_type(8)));
typedef float    f32x4 __attribute__((ext_vector_type(4)));
typedef unsigned long long u64;
typedef u64 u64x2 __attribute__((ext_vector_type(2)));

constexpr int BATCH = 1024;
constexpr int HDIM  = 512;
constexpr int TENC  = 512;
constexpr int PRED  = 48;
constexpr int STEPS = TENC + PRED - 1;   // 559 cell steps; loop runs 560 (last = fc only)
constexpr int NG    = 64;                // groups (16 batches each)
constexpr int GB    = 16;                // batches per group = one MFMA m-tile
constexpr int UBU   = 64;                // units per block (4 waves x 16)
constexpr int HB_OFF = 32768;

// In-band tag (R7/R8-proven): each 4B dword of stored h carries step tag at
// bit0/bit16. h_t in buffer t&1, tag t&3; skew <= 1 step => ABA-safe.
// LLC scope only (R10: per-XCD L2 is NOT a usable exchange medium).
constexpr u64 TAG_MASK = 0x0001000100010001ull;
__device__ __forceinline__ u64 tag_of(int t) {
  return ((u64)(t & 1) | ((u64)((t >> 1) & 1) << 16)) * 0x0000000100000001ull;
}

__global__ void init_kernel(int* wsi) {
  int idx = blockIdx.x * blockDim.x + threadIdx.x;
  int stride = gridDim.x * blockDim.x;
  const int nws = (HB_OFF + BATCH * HDIM * 2) / 4;  // hbuf[0] = h_0 = 0 (tag 00)
  for (int i = idx; i < nws; i += stride) wsi[i] = 0;
  // hbuf[1] stays 0xAA poison -> tag-invalid until written
}

static __device__ __forceinline__ f16x8 load16_llc(const _Float16* p) {
  f16x8 v;
  asm volatile("global_load_dwordx4 %0, %1, off sc0 sc1"
               : "=v"(v) : "v"((u64)p) : "memory");
  return v;
}
static __device__ __forceinline__ float loadx(const float* p) {
  float v;   // plain cached load via asm so compiler never vmcnt(0)-drains our prefetch
  asm volatile("global_load_dword %0, %1, off"
               : "=v"(v) : "v"((u64)p) : "memory");
  return v;
}

// R11 structure (best: 3497us) with race-free prefetch timing:
//  - A(t+1) h-prefetch issued AFTER gemm(hsB) (was: before it) -> slow
//    A-producers get the whole B-GEMM as grace -> first-probe fresh.
//  - x prefetched one phase early (xB during phase A, xA(t+1) during
//    phase B) -> x RT never sits on the phase-top drain.
// No burners (R12: DPM unmoved by VALU heat). No flags/fences: in-band tags.
__global__ __launch_bounds__(256, 1) void lstm_persist(
    const float* __restrict__ x,
    const float* __restrict__ w_ih,
    const float* __restrict__ w_hh,
    const float* __restrict__ b_ih,
    const float* __restrict__ b_hh,
    const float* __restrict__ w_fc,
    const float* __restrict__ b_fc,
    float* __restrict__ out,          // [1024][48] fp32, plain stores
    _Float16* __restrict__ hbuf)      // [2][1024][512] fp16 ping-pong, tagged
{
  const int bid  = blockIdx.x;
  const int gA   = bid >> 3;          // group A (0..31); B = gA+32
  const int ub   = bid & 7;
  const int tid  = threadIdx.x;
  const int wid  = tid >> 6;
  const int lane = tid & 63;
  const int quad = lane >> 4;
  const int lcol = lane & 15;
  const int bA0  = gA * GB;
  const int bB0  = bA0 + NG / 2 * GB; // = bA0 + 512
  const int myu  = ub * UBU + wid * 16 + lcol;
  const int uoff = ub * UBU + wid * 16 + (lcol & ~3);

  __shared__ __align__(16) _Float16 hsA[GB][520];    // 16.6 KB
  __shared__ __align__(16) _Float16 hsB[GB][520];    // 16.6 KB
  __shared__ __align__(16) _Float16 wz[520];         // fp16 w_fc + zero pad

  for (int k = tid; k < 512; k += 256) wz[k] = (_Float16)w_fc[k];
  if (tid < 8) wz[512 + tid] = (_Float16)0.f;

  // ---- full-K weight B-frags (n=lcol, k=kc*32+quad*8+j) ----
  f16x8 wf[4][16];
  float wih[4], bias[4];
#pragma unroll
  for (int nt = 0; nt < 4; ++nt) {
    const int j = nt * HDIM + myu;
    wih[nt]  = w_ih[j];
    bias[nt] = b_ih[j] + b_hh[j];
#pragma unroll
    for (int kc = 0; kc < 16; ++kc) {
      const float* s = w_hh + (size_t)j * HDIM + kc * 32 + quad * 8;
      f16x8 v;
#pragma unroll
      for (int i = 0; i < 8; ++i) v[i] = (_Float16)s[i];
      wf[nt][kc] = v;
    }
  }
  const float bfc = b_fc[0];

  float cstA[4], cstB[4];
#pragma unroll
  for (int r = 0; r < 4; ++r) { cstA[r] = 0.f; cstB[r] = 0.f; }

  // staging: 16 rows x 512 units = 1024 16B-chunks; thread covers 4
  // (c = i*256+tid: row=c>>6, col16=c&63). Own slice included (own
  // store->load via LLC is same-thread ordered; R7-verified).
  f16x8 tA[4], tB[4];
  float xA[4], xB[4];

  auto issue4 = [&](f16x8* tr, const _Float16* base) {
#pragma unroll
    for (int i = 0; i < 4; ++i) {
      const int c = i * 256 + tid;
      tr[i] = load16_llc(base + (size_t)(c >> 6) * HDIM + (c & 63) * 8);
    }
  };
  auto validate4 = [&](f16x8* tr, const _Float16* base, u64 expect) {
    unsigned stale = 0xf;
    for (;;) {
      unsigned ns = 0;
#pragma unroll
      for (int i = 0; i < 4; ++i)
        if (stale & (1u << i)) {
          u64x2 w2 = __builtin_bit_cast(u64x2, tr[i]);
          if (((w2[0] & TAG_MASK) != expect) || ((w2[1] & TAG_MASK) != expect))
            ns |= 1u << i;
        }
      if (ns == 0) break;
      __builtin_amdgcn_s_sleep(1);
#pragma unroll
      for (int i = 0; i < 4; ++i)
        if (ns & (1u << i)) {
          const int c = i * 256 + tid;
          tr[i] = load16_llc(base + (size_t)(c >> 6) * HDIM + (c & 63) * 8);
        }
      asm volatile("s_waitcnt vmcnt(0)" ::: "memory");
      stale = ns;
    }
  };
  auto stage4 = [&](f16x8* tr, _Float16 (*hsp)[520]) {
#pragma unroll
    for (int i = 0; i < 4; ++i) {
      const int c = i * 256 + tid;
      *reinterpret_cast<f16x8*>(&hsp[c >> 6][(c & 63) * 8]) = tr[i];
    }
  };
  auto gemm = [&](const _Float16 (*hsp)[520], f32x4* acc, f32x4& accF, bool dec) {
#pragma unroll
    for (int kc = 0; kc < 16; ++kc) {
      const f16x8 a = *reinterpret_cast<const f16x8*>(&hsp[lcol][kc * 32 + quad * 8]);
#pragma unroll
      for (int nt = 0; nt < 4; ++nt)
        acc[nt] = __builtin_amdgcn_mfma_f32_16x16x32_f16(a, wf[nt][kc], acc[nt], 0, 0, 0);
      if (dec) {   // fc: B row 0 = w_fc, rows 1..15 = 0 (zero-pad broadcast)
        const f16x8 wv = *reinterpret_cast<const f16x8*>(
            &wz[(lcol == 0) ? (kc * 32 + quad * 8) : 512]);
        accF = __builtin_amdgcn_mfma_f32_16x16x32_f16(a, wv, accF, 0, 0, 0);
      }
    }
  };
  auto tail = [&](f32x4* acc, f32x4& accF, float* xv, float* cstv,
                  int bX0, int t, _Float16* hnxt, bool dec) {
    if (dec) {   // xt = fc(h_t), redundant per block; preds stored by ub0/w0
#pragma unroll
      for (int r = 0; r < 4; ++r) xv[r] = __shfl(accF[r], quad * 16) + bfc;
      if (ub == 0 && wid == 0 && lcol == 0) {
        const int p = t - TENC;
#pragma unroll
        for (int r = 0; r < 4; ++r)
          out[(size_t)(bX0 + quad * 4 + r) * PRED + p] = accF[r] + bfc;
      }
    }
    if (t < STEPS) {
      const u64 tagnew = tag_of(t + 1);
#pragma unroll
      for (int r = 0; r < 4; ++r) {
        const float xt = xv[r];
        const float gi = acc[0][r] + xt * wih[0] + bias[0];
        const float gf = acc[1][r] + xt * wih[1] + bias[1];
        const float gg = acc[2][r] + xt * wih[2] + bias[2];
        const float go = acc[3][r] + xt * wih[3] + bias[3];
        const float si = 1.f / (1.f + __expf(-gi));
        const float sf = 1.f / (1.f + __expf(-gf));
        const float so = 1.f / (1.f + __expf(-go));
        const float tg = 1.f - 2.f / (1.f + __expf(2.f * gg));
        const float cn = sf * cstv[r] + si * tg;
        cstv[r] = cn;
        const float tc = 1.f - 2.f / (1.f + __expf(2.f * cn));
        const float hn = so * tc;

        const unsigned short hb = __builtin_bit_cast(unsigned short, (_Float16)hn);
        const unsigned v0  = hb;
        const unsigned o0  = (unsigned)__shfl_xor((int)v0, 1);
        const unsigned p01 = (lcol & 1) ? ((v0 << 16) | o0) : ((o0 << 16) | v0);
        const unsigned q   = (unsigned)__shfl_xor((int)p01, 2);
        u64 p4 = (lcol & 2) ? (((u64)p01 << 32) | (u64)q)
                            : (((u64)q << 32) | (u64)p01);
        p4 = (p4 & ~TAG_MASK) | tagnew;
        if ((lcol & 3) == r) {
          _Float16* dst = hnxt + (size_t)(bX0 + quad * 4 + r) * HDIM + uoff;
          __hip_atomic_store((u64*)dst, p4, __ATOMIC_RELAXED,
                             __HIP_MEMORY_SCOPE_AGENT);
        }
      }
    }
  };

  // prologue: A(0) h + x in flight
  issue4(tA, hbuf + (size_t)bA0 * HDIM);
#pragma unroll
  for (int r = 0; r < 4; ++r)
    xA[r] = loadx(x + (size_t)(bA0 + quad * 4 + r) * TENC + 0);

  for (int t = 0; t <= STEPS; ++t) {
    const _Float16* hcur = hbuf + (size_t)(t & 1) * BATCH * HDIM;
    _Float16*       hnxt = hbuf + (size_t)((t + 1) & 1) * BATCH * HDIM;
    const u64 expect = tag_of(t);
    const bool dec = (t >= TENC);

    // ================= phase A =================
    asm volatile("s_waitcnt vmcnt(0)" ::: "memory");   // tA + xA landed
    validate4(tA, hcur + (size_t)bA0 * HDIM, expect);
    stage4(tA, hsA);
    __syncthreads();
    issue4(tB, hcur + (size_t)bB0 * HDIM);   // B(t): published t-1 -> fresh
    if (!dec) {                              // xB(t) prefetch, lands with tB
#pragma unroll
      for (int r = 0; r < 4; ++r)
        xB[r] = loadx(x + (size_t)(bB0 + quad * 4 + r) * TENC + t);
    }

    f32x4 accA[4], accFA;
#pragma unroll
    for (int nt = 0; nt < 4; ++nt) accA[nt] = (f32x4){0.f, 0.f, 0.f, 0.f};
    accFA = (f32x4){0.f, 0.f, 0.f, 0.f};
    gemm(hsA, accA, accFA, dec);
    tail(accA, accFA, xA, cstA, bA0, t, hnxt, dec);

    // ================= phase B =================
    asm volatile("s_waitcnt vmcnt(0)" ::: "memory");   // tB + xB landed
    validate4(tB, hcur + (size_t)bB0 * HDIM, expect);
    stage4(tB, hsB);
    __syncthreads();

    f32x4 accB[4], accFB;
#pragma unroll
    for (int nt = 0; nt < 4; ++nt) accB[nt] = (f32x4){0.f, 0.f, 0.f, 0.f};
    accFB = (f32x4){0.f, 0.f, 0.f, 0.f};
    gemm(hsB, accB, accFB, dec);

    // A(t+1) prefetch AFTER B-GEMM: slow A-producers had the whole B-GEMM
    // to publish -> first-probe fresh (R11 issued this pre-GEMM: stale race,
    // FETCH 2.3GB of reloads). Flies during tail(B) + loop-around.
    if (t < STEPS) {
      issue4(tA, hnxt + (size_t)bA0 * HDIM);
      if (t + 1 < TENC) {
#pragma unroll
        for (int r = 0; r < 4; ++r)
          xA[r] = loadx(x + (size_t)(bA0 + quad * 4 + r) * TENC + (t + 1));
      }
    }

    tail(accB, accFB, xB, cstB, bB0, t, hnxt, dec);
  }
}

extern "C" void kernel_launch(void* const* d_in, const int* in_sizes, int n_in,
                              void* d_out, int out_size, void* d_ws, size_t ws_size,
                              hipStream_t stream) {
  const float* x    = (const float*)d_in[0];
  const float* w_ih = (const float*)d_in[1];
  const float* w_hh = (const float*)d_in[2];
  const float* b_ih = (const float*)d_in[3];
  const float* b_hh = (const float*)d_in[4];
  const float* w_fc = (const float*)d_in[5];
  const float* b_fc = (const float*)d_in[6];
  float* out = (float*)d_out;
  _Float16* hbuf = (_Float16*)((char*)d_ws + HB_OFF);

  hipLaunchKernelGGL(init_kernel, dim3(256), dim3(256), 0, stream, (int*)d_ws);
  hipLaunchKernelGGL(lstm_persist, dim3(256), dim3(256), 0, stream,
                     x, w_ih, w_hh, b_ih, b_hh, w_fc, b_fc, out, hbuf);
}